// Round 10
// baseline (619.166 us; speedup 1.0000x reference)
//
#include <hip/hip_runtime.h>

// Boosted neural LDPC min-sum decoder, MI355X — ONE kernel: block = batch,
// __syncthreads between phases (no kernel-boundary / grid-sync cost).
// Msg planes + lt + xat in global (L2-local); tables + transpose tile in LDS.
// Sizes fixed by setup_inputs(): B=32, Z=384, N=68, M=46, dc=7, E=322, iters=8.
#define B_   32
#define Z_   384
#define N_   68
#define M_   46
#define DC_  7
#define E_   (M_ * DC_)      // 322
#define ZN   (Z_ * N_)       // 26112
#define ZM   (Z_ * M_)       // 17664
#define MSB  (DC_ * ZM)      // 123648 bytes of messages per batch (7 planes)

// ---- workspace layout (int32 offsets) ----
#define XAT_OFF   0                          // float xat[B*ZN]   z-fastest
#define LT_OFF    (B_ * ZN)                  // float lt[B*ZN]    z-fastest
#define MSG_OFF   (2 * B_ * ZN)              // sbyte msg[B][7][ZM]  plane-major
#define MSG_INTS  ((B_ * MSB + 3) / 4)
#define WS_INTS   (MSG_OFF + MSG_INTS)       // ~2.66M ints ≈ 10.6 MB

// msg[b][j][m*Z+z] = c2v message on edge j of check (m,z), sign applied, in
// half-steps, range [-15,15]. Exact ints -> fp arithmetic identical to JAX ref.

// ==================== the whole decoder in one kernel ====================
__global__ __launch_bounds__(1024)
void k_all(const float* __restrict__ xa, const float* __restrict__ cw,
           const int* __restrict__ vn_idx, const int* __restrict__ shifts,
           float* __restrict__ xat_g, float* __restrict__ lt_g,
           signed char* __restrict__ msg_g, float* __restrict__ out, int iters)
{
    __shared__ int   evs[E_];      // pass-B records: (vn*Z)<<9 | s   (check-major)
    __shared__ int   lists[E_];    // pass-A records: (j*ZM+m*Z)<<9 | s  (CSR by n)
    __shared__ int   offs[N_ + 1];
    __shared__ float wlds[8];
    __shared__ float tile[N_ * 65];          // transpose tile; also temp for build

    const int tid = threadIdx.x;
    const int b   = blockIdx.x;

    // ---- table build (every block builds identical tables; ~µs) ----
    int* vnl = (int*)tile;                   // temp in tile space
    int* shl = vnl + E_;
    if (tid < E_) { vnl[tid] = vn_idx[tid]; shl[tid] = shifts[tid]; }
    if (tid < 8) wlds[tid] = cw[tid];
    __syncthreads();
    if (tid < N_) {
        int c = 0;
        for (int e = 0; e < E_; ++e) c += (vnl[e] == tid);
        offs[tid + 1] = c;
    }
    if (tid == 0) offs[0] = 0;
    __syncthreads();
    if (tid == 0) { for (int n = 0; n < N_; ++n) offs[n + 1] += offs[n]; }
    __syncthreads();
    if (tid < E_) evs[tid] = (vnl[tid] * Z_ << 9) | shl[tid];
    if (tid < N_) {
        int p = offs[tid];
        for (int e = 0; e < E_; ++e) {
            if (vnl[e] == tid) {
                int m = e / DC_, j = e - m * DC_;
                lists[p++] = ((j * ZM + m * Z_) << 9) | shl[e];
            }
        }
    }
    __syncthreads();

    // ---- transpose this batch: xat[b][n][z] = xa[b][z][n] ----
    const float* xab = xa + (size_t)b * ZN;
    float* tdst = ((iters == 0) ? out : xat_g) + (size_t)b * ZN;
    for (int t = 0; t < 6; ++t) {
        const int z0 = t * 64;
        const float* src = xab + (size_t)z0 * N_;
        for (int i = tid; i < 64 * N_; i += 1024) {   // contiguous 17 KB read
            int r = i / N_, n = i - r * N_;
            tile[n * 65 + r] = src[i];
        }
        __syncthreads();
        for (int i = tid; i < 64 * N_; i += 1024) {
            int n = i >> 6, zl = i & 63;
            tdst[n * Z_ + z0 + zl] = tile[n * 65 + zl];
        }
        __syncthreads();
    }
    if (iters == 0) return;                   // out = transpose(xa)

    const float* xb = xat_g + (size_t)b * ZN;
    float*       lb = lt_g + (size_t)b * ZN;
    signed char* mb = msg_g + (size_t)b * MSB;

    // ================= iteration loop: B0, (A,B)x(iters-1), A ==============
    for (int it = 0; it < iters; ++it) {
        // ---- pass B: check-node update (reads src + own old msg bytes) ----
        const float* src = (it == 0) ? xb : lb;
        const float w = wlds[it];
        const int use_init = (it == 0);
        for (int l = tid; l < ZM; l += 1024) {
            const int m = l / Z_;
            const int z = l - m * Z_;
            float m1 = 1e30f, m2 = 1e30f;
            int f = 0, negb = 0;
            #pragma unroll
            for (int j = 0; j < DC_; ++j) {
                int rec = evs[m * DC_ + j];
                int s = rec & 511;
                int zr = z + s; if (zr >= Z_) zr -= Z_;
                int c2 = use_init ? 0 : (int)mb[j * ZM + l];   // own old, exact int
                // identical operand order to JAX: fl(fl(llr+tot) - c2v), clip
                float v = src[(rec >> 9) + zr] - 0.5f * (float)c2;
                v = fminf(fmaxf(v, -20.0f), 20.0f);
                negb |= (v < 0.0f) << j;
                float a = fabsf(v);
                if (a < m1) { m2 = m1; m1 = a; f = j; }
                else if (a < m2) { m2 = a; }
            }
            // quantize-STE fwd: clip(rint(2*w*min)/2, +-7.5), int half-steps
            float r1 = fminf(fmaxf(rintf(w * m1 * 2.0f), -15.0f), 15.0f);
            float r2 = fminf(fmaxf(rintf(w * m2 * 2.0f), -15.0f), 15.0f);
            const int q1 = (int)r1, q2 = (int)r2;
            const int par = __popc(negb);
            #pragma unroll
            for (int j = 0; j < DC_; ++j) {
                int q  = (j == f) ? q2 : q1;
                int sj = (par - ((negb >> j) & 1)) & 1;  // parity of others' signs
                mb[j * ZM + l] = (signed char)(sj ? -q : q);
            }
        }
        __syncthreads();                       // msg visible to pass A

        // ---- pass A: variable totals -> lt (or out on last iteration) ----
        float* dst = (it == iters - 1) ? (out + (size_t)b * ZN) : lb;
        for (int l = tid; l < ZN; l += 1024) {
            const int n = l / Z_;
            const int z = l - n * Z_;
            const int o = offs[n], e = offs[n + 1];  // wave-uniform (64 | Z)
            int t2 = 0;
            for (int k = o; k < e; ++k) {
                int rec = lists[k];
                int s = rec & 511;
                int zs = z - s; if (zs < 0) zs += Z_;
                t2 += (int)mb[(rec >> 9) + zs];       // exact int half-steps
            }
            dst[l] = xb[l] + 0.5f * (float)t2;        // fl(llr + tot)
        }
        __syncthreads();                       // lt visible to next pass B
    }
}

// ==================== fallback: single-block-per-batch kernel (small ws) ====================
#define INIT_STATE ((16u << 10) | (16u << 15))
__device__ __forceinline__ int decode2(unsigned st, int j) {
    int neg   = (st >> j) & 1;
    int q1    = (int)((st >> 10) & 31) - 16;
    int q2    = (int)((st >> 15) & 31) - 16;
    int first = (int)((st >> 7) & 7);
    int q     = (j == first) ? q2 : q1;
    int par   = (__popc(st & 127u) - neg) & 1;
    return par ? -q : q;
}

__global__ __launch_bounds__(1024)
void ldpc_decode_kernel(const float* __restrict__ xa,
                        const float* __restrict__ cw,
                        const int*   __restrict__ vn_idx,
                        const int*   __restrict__ shifts,
                        float* out, int iters)
{
    __shared__ short tot[ZN];
    __shared__ int   evs[E_];
    __shared__ int   offs[N_ + 1];
    __shared__ int   lists[E_];
    __shared__ float wlds[8];

    const int tid = threadIdx.x;
    const int b   = blockIdx.x;
    const float* xab = xa + (size_t)b * ZN;
    float* outb = out + (size_t)b * ZN;
    int* stateg = (int*)outb;

    if (tid < E_) evs[tid] = vn_idx[tid] | (shifts[tid] << 7);
    if (tid < iters && tid < 8) wlds[tid] = cw[tid];
    __syncthreads();
    if (tid < N_) {
        int c = 0;
        for (int e = 0; e < E_; ++e) c += ((evs[e] & 127) == tid);
        offs[tid + 1] = c;
    }
    if (tid == 0) offs[0] = 0;
    __syncthreads();
    if (tid == 0) { for (int n = 0; n < N_; ++n) offs[n + 1] += offs[n]; }
    __syncthreads();
    if (tid < N_) {
        int p = offs[tid];
        for (int e = 0; e < E_; ++e) {
            int rec = evs[e];
            if ((rec & 127) == tid) {
                int s = rec >> 7;
                lists[p++] = s | ((e / DC_) << 9) | ((e % DC_) << 15);
            }
        }
    }
    __syncthreads();

    for (int i = tid; i < ZM; i += 1024) stateg[i] = (int)INIT_STATE;
    __syncthreads();

    for (int it = 0; it < iters; ++it) {
        for (int i = tid; i < ZN; i += 1024) {
            int z = i / N_, n = i - z * N_, t2 = 0;
            int kend = offs[n + 1];
            for (int k = offs[n]; k < kend; ++k) {
                int rec = lists[k];
                int s = rec & 511, m = (rec >> 9) & 63, j = rec >> 15;
                int zs = z - s; if (zs < 0) zs += Z_;
                t2 += decode2((unsigned)stateg[zs * M_ + m], j);
            }
            tot[i] = (short)t2;
        }
        __syncthreads();
        const float w = wlds[it];
        for (int i = tid; i < ZM; i += 1024) {
            int z = i / M_, m = i - z * M_;
            unsigned st = (unsigned)stateg[i];
            float m1 = 1e30f, m2 = 1e30f;
            int f = 0, negb = 0;
            #pragma unroll
            for (int j = 0; j < DC_; ++j) {
                int rec = evs[m * DC_ + j];
                int vn = rec & 127, s = rec >> 7;
                int zr = z + s; if (zr >= Z_) zr -= Z_;
                int c2 = decode2(st, j);
                int idx = zr * N_ + vn;
                float v = (xab[idx] + 0.5f * (float)tot[idx]) - 0.5f * (float)c2;
                v = fminf(fmaxf(v, -20.0f), 20.0f);
                negb |= (v < 0.0f) << j;
                float a = fabsf(v);
                if (a < m1) { m2 = m1; m1 = a; f = j; }
                else if (a < m2) { m2 = a; }
            }
            float r1 = fminf(fmaxf(rintf(w * m1 * 2.0f), -15.0f), 15.0f);
            float r2 = fminf(fmaxf(rintf(w * m2 * 2.0f), -15.0f), 15.0f);
            stateg[i] = (int)(unsigned)(negb | (f << 7) | (((int)r1 + 16) << 10) | (((int)r2 + 16) << 15));
        }
        __syncthreads();
    }

    for (int i = tid; i < ZN; i += 1024) {
        int z = i / N_, n = i - z * N_, t2 = 0;
        int kend = offs[n + 1];
        for (int k = offs[n]; k < kend; ++k) {
            int rec = lists[k];
            int s = rec & 511, m = (rec >> 9) & 63, j = rec >> 15;
            int zs = z - s; if (zs < 0) zs += Z_;
            t2 += decode2((unsigned)stateg[zs * M_ + m], j);
        }
        tot[i] = (short)t2;
    }
    __syncthreads();
    for (int i = tid; i < ZN; i += 1024) {
        int n = i / Z_, z = i - n * Z_;
        outb[i] = xab[z * N_ + n] + 0.5f * (float)tot[z * N_ + n];
    }
}

extern "C" void kernel_launch(void* const* d_in, const int* in_sizes, int n_in,
                              void* d_out, int out_size, void* d_ws, size_t ws_size,
                              hipStream_t stream) {
    const float* xa = (const float*)d_in[0];
    const float* cw = (const float*)d_in[1];
    const int* vn   = (const int*)d_in[2];
    // d_in[3] = cn_idx: repeat(arange(M), dc) by construction — implicit.
    const int* sh   = (const int*)d_in[4];
    int iters = in_sizes[1];
    float* outp = (float*)d_out;

    if (ws_size >= (size_t)WS_INTS * sizeof(int)) {
        int*         ws  = (int*)d_ws;
        float*       xat = (float*)d_ws + XAT_OFF;
        float*       lt  = (float*)d_ws + LT_OFF;
        signed char* msg = (signed char*)(ws + MSG_OFF);

        hipLaunchKernelGGL(k_all, dim3(B_), dim3(1024), 0, stream,
                           xa, cw, vn, sh, xat, lt, msg, outp, iters);
    } else {
        hipLaunchKernelGGL(ldpc_decode_kernel, dim3(B_), dim3(1024), 0, stream,
                           xa, cw, vn, sh, outp, iters);
    }
}

// Round 11
// 308.912 us; speedup vs baseline: 2.0043x; 2.0043x over previous
//
#include <hip/hip_runtime.h>

// Boosted neural LDPC min-sum decoder, MI355X — persistent kernel with
// BATCH-LOCAL flag barriers (8 blocks/batch, no atomic RMW, no shared line).
// Plane-major int8 messages, z-fastest fp32 arrays, XCD-swizzled mapping.
// Sizes fixed by setup_inputs(): B=32, Z=384, N=68, M=46, dc=7, E=322, iters=8.
#define B_   32
#define Z_   384
#define N_   68
#define M_   46
#define DC_  7
#define E_   (M_ * DC_)      // 322
#define ZN   (Z_ * N_)       // 26112
#define ZM   (Z_ * M_)       // 17664
#define MSB  (DC_ * ZM)      // 123648 bytes of messages per batch (7 planes)
#define ZM_S (ZM / 8)        // 2208 pass-B items per slice
#define ZN_S (ZN / 8)        // 3264 pass-A items per slice

// ---- workspace layout (int32 offsets) ----
#define XAT_OFF   0                          // float xat[B*ZN]   z-fastest
#define LT_OFF    (B_ * ZN)                  // float lt[B*ZN]    z-fastest
#define MSG_OFF   (2 * B_ * ZN)              // sbyte msg[B][7][ZM]  plane-major
#define MSG_INTS  ((B_ * MSB + 3) / 4)
#define FLG_OFF   (MSG_OFF + MSG_INTS)       // int flags[B][8] @ 64B stride
#define FLG_INTS  (B_ * 128)
#define EVS_OFF   (FLG_OFF + FLG_INTS)       // int evs[E]    (vn*Z)<<9 | s
#define OFFS_OFF  (EVS_OFF + E_)             // int offs[N+1] CSR per variable
#define LST_OFF   (OFFS_OFF + N_ + 1)        // int lists[E]  (j*ZM+m*Z)<<9 | s
#define WS_INTS   (LST_OFF + E_)             // ~2.67M ints ≈ 10.7 MB

// msg[b][j][m*Z+z] = c2v message on edge j of check (m,z), sign applied, in
// half-steps, range [-15,15]. Exact ints -> fp arithmetic identical to JAX ref.

// ==================== merged pre-transpose + table build + flag init ========
// Blocks 0..191: xat[b][n][z] = xa[b][z][n] (XCD-swizzled). Block 192: tables.
__global__ __launch_bounds__(384)
void k_pre_tables(const float* __restrict__ xa,
                  const int* __restrict__ vn_idx, const int* __restrict__ shifts,
                  int* __restrict__ ws, float* __restrict__ xat_dst)
{
    const int tid = threadIdx.x;
    if (blockIdx.x == B_ * 6) {
        // ---- table build (1 block) + barrier-flag zeroing ----
        __shared__ int vnl[E_];
        __shared__ int shl[E_];
        __shared__ int offs[N_ + 1];
        if (tid < E_) { vnl[tid] = vn_idx[tid]; shl[tid] = shifts[tid]; }
        for (int i = tid; i < FLG_INTS; i += 384) ws[FLG_OFF + i] = 0;
        __syncthreads();
        if (tid < N_) {
            int c = 0;
            for (int e = 0; e < E_; ++e) c += (vnl[e] == tid);
            offs[tid + 1] = c;
        }
        if (tid == 0) offs[0] = 0;
        __syncthreads();
        if (tid == 0) { for (int n = 0; n < N_; ++n) offs[n + 1] += offs[n]; }
        __syncthreads();
        if (tid < E_) ws[EVS_OFF + tid] = (vnl[tid] * Z_ << 9) | shl[tid];
        if (tid < N_ + 1) ws[OFFS_OFF + tid] = offs[tid];
        if (tid < N_) {
            int p = offs[tid];
            for (int e = 0; e < E_; ++e) {
                if (vnl[e] == tid) {
                    int m = e / DC_, j = e - m * DC_;
                    ws[LST_OFF + p++] = ((j * ZM + m * Z_) << 9) | shl[e];
                }
            }
        }
        return;
    }
    // ---- pre-transpose: block = swizzled (b, 64-z tile) ----
    __shared__ float tile[N_ * 65];           // [n][zl], pad 65 to break conflicts
    const int x = blockIdx.x & 7;
    const int k = blockIdx.x >> 3;            // 0..23
    const int b = x + 8 * (k & 3);            // b % 8 == x  -> XCD locality
    const int t = k >> 2;                     // 0..5
    const int z0 = t * 64;
    const float* src = xa + (size_t)b * ZN + (size_t)z0 * N_;
    for (int i = tid; i < 64 * N_; i += 384) {  // contiguous 17 KB read
        int r = i / N_, n = i - r * N_;
        tile[n * 65 + r] = src[i];
    }
    __syncthreads();
    float* dst = xat_dst + (size_t)b * ZN + z0;
    for (int i = tid; i < 64 * N_; i += 384) {
        int n = i >> 6, zl = i & 63;
        dst[n * Z_ + zl] = tile[n * 65 + zl];
    }
}

// ==================== batch-local barrier (8 blocks, flag per slice) ========
// Release-store own flag, spin (relaxed) on all 8, then one acquire fence.
// No atomic RMW; flags 64B apart -> no line ping-pong on arrival.
__device__ __forceinline__ void bbar(int* flg, int sl, unsigned phase)
{
    __syncthreads();                          // all waves' stores drained to L2
    if (threadIdx.x == 0)
        __hip_atomic_store(&flg[sl * 16], (int)phase, __ATOMIC_RELEASE,
                           __HIP_MEMORY_SCOPE_AGENT);   // wbl2 + store
    if (threadIdx.x < 8) {
        while ((unsigned)__hip_atomic_load(&flg[threadIdx.x * 16],
                 __ATOMIC_RELAXED, __HIP_MEMORY_SCOPE_AGENT) < phase)
            __builtin_amdgcn_s_sleep(1);
    }
    __syncthreads();                          // all 8 flags seen
    if (threadIdx.x == 0) __threadfence();    // acquire: invalidate stale caches
    __syncthreads();
}

// ==================== pass bodies (R9 logic, slice-local) ===================
__device__ __forceinline__ void passB_slice(int lo, const float* __restrict__ src,
                                            signed char* __restrict__ mb, float w,
                                            const int* __restrict__ evs,
                                            int use_init, int tid)
{
    const int hi = lo + ZM_S;
    for (int l = lo + tid; l < hi; l += 1024) {
        const int m = l / Z_;
        const int z = l - m * Z_;
        float m1 = 1e30f, m2 = 1e30f;
        int f = 0, negb = 0;
        #pragma unroll
        for (int j = 0; j < DC_; ++j) {
            int rec = evs[m * DC_ + j];
            int s = rec & 511;
            int zr = z + s; if (zr >= Z_) zr -= Z_;
            int c2 = use_init ? 0 : (int)mb[j * ZM + l];   // own old msg, exact int
            // identical operand order to JAX: fl(fl(llr + tot) - c2v), then clip
            float v = src[(rec >> 9) + zr] - 0.5f * (float)c2;
            v = fminf(fmaxf(v, -20.0f), 20.0f);
            negb |= (v < 0.0f) << j;
            float a = fabsf(v);
            if (a < m1) { m2 = m1; m1 = a; f = j; }
            else if (a < m2) { m2 = a; }
        }
        // quantize-STE fwd: clip(rint(2*w*min)/2, +-7.5), int half-steps
        float r1 = fminf(fmaxf(rintf(w * m1 * 2.0f), -15.0f), 15.0f);
        float r2 = fminf(fmaxf(rintf(w * m2 * 2.0f), -15.0f), 15.0f);
        const int q1 = (int)r1, q2 = (int)r2;
        const int par = __popc(negb);
        #pragma unroll
        for (int j = 0; j < DC_; ++j) {
            int q  = (j == f) ? q2 : q1;
            int sj = (par - ((negb >> j) & 1)) & 1;   // parity of others' signs
            mb[j * ZM + l] = (signed char)(sj ? -q : q);
        }
    }
}

__device__ __forceinline__ void passA_slice(int lo, const float* __restrict__ xb,
                                            const signed char* __restrict__ mb,
                                            float* __restrict__ dst,
                                            const int* __restrict__ offs,
                                            const int* __restrict__ lists, int tid)
{
    const int hi = lo + ZN_S;
    for (int l = lo + tid; l < hi; l += 1024) {
        const int n = l / Z_;
        const int z = l - n * Z_;
        const int o = offs[n], e = offs[n + 1];
        int t2 = 0;
        for (int k = o; k < e; ++k) {
            int rec = lists[k];
            int s = rec & 511;
            int zs = z - s; if (zs < 0) zs += Z_;
            t2 += (int)mb[(rec >> 9) + zs];       // exact int half-steps
        }
        dst[l] = xb[l] + 0.5f * (float)t2;        // fl(llr + tot)
    }
}

// ==================== persistent kernel: 256 blocks, batch-local sync =======
// block g: x=g&7, b = x + 8*((g>>3)&3) (b%8==x -> XCD locality), sl = g>>5.
__global__ __launch_bounds__(1024)
void k_persist(const float* __restrict__ xat, const float* __restrict__ cw,
               int* __restrict__ ws, signed char* __restrict__ msg,
               float* __restrict__ lt, float* __restrict__ out, int iters)
{
    __shared__ int   evs[E_];
    __shared__ int   lists[E_];
    __shared__ int   offs[N_ + 1];
    __shared__ float wlds[8];
    const int tid = threadIdx.x;
    if (tid < E_) { evs[tid] = ws[EVS_OFF + tid]; lists[tid] = ws[LST_OFF + tid]; }
    if (tid < N_ + 1) offs[tid] = ws[OFFS_OFF + tid];
    if (tid < 8) wlds[tid] = cw[tid];
    __syncthreads();

    const int x  = blockIdx.x & 7;
    const int kk = blockIdx.x >> 3;
    const int b  = x + 8 * (kk & 3);
    const int sl = kk >> 2;                    // 0..7
    int* flg = ws + FLG_OFF + b * 128;

    const float* xb = xat + (size_t)b * ZN;
    float*       lb = lt + (size_t)b * ZN;
    signed char* mb = msg + (size_t)b * MSB;
    const int bLo = sl * ZM_S;
    const int aLo = sl * ZN_S;
    unsigned phase = 0;

    // it = 0: lt_old == xat, all old c2v == 0
    passB_slice(bLo, xb, mb, wlds[0], evs, 1, tid);
    for (int it = 1; it < iters; ++it) {
        bbar(flg, sl, ++phase);
        passA_slice(aLo, xb, mb, lb, offs, lists, tid);
        bbar(flg, sl, ++phase);
        passB_slice(bLo, lb, mb, wlds[it], evs, 0, tid);
    }
    bbar(flg, sl, ++phase);
    passA_slice(aLo, xb, mb, out + (size_t)b * ZN, offs, lists, tid);
}

// ==================== fallback: single-block-per-batch kernel (small ws) ====
#define INIT_STATE ((16u << 10) | (16u << 15))
__device__ __forceinline__ int decode2(unsigned st, int j) {
    int neg   = (st >> j) & 1;
    int q1    = (int)((st >> 10) & 31) - 16;
    int q2    = (int)((st >> 15) & 31) - 16;
    int first = (int)((st >> 7) & 7);
    int q     = (j == first) ? q2 : q1;
    int par   = (__popc(st & 127u) - neg) & 1;
    return par ? -q : q;
}

__global__ __launch_bounds__(1024)
void ldpc_decode_kernel(const float* __restrict__ xa,
                        const float* __restrict__ cw,
                        const int*   __restrict__ vn_idx,
                        const int*   __restrict__ shifts,
                        float* out, int iters)
{
    __shared__ short tot[ZN];
    __shared__ int   evs[E_];
    __shared__ int   offs[N_ + 1];
    __shared__ int   lists[E_];
    __shared__ float wlds[8];

    const int tid = threadIdx.x;
    const int b   = blockIdx.x;
    const float* xab = xa + (size_t)b * ZN;
    float* outb = out + (size_t)b * ZN;
    int* stateg = (int*)outb;

    if (tid < E_) evs[tid] = vn_idx[tid] | (shifts[tid] << 7);
    if (tid < iters && tid < 8) wlds[tid] = cw[tid];
    __syncthreads();
    if (tid < N_) {
        int c = 0;
        for (int e = 0; e < E_; ++e) c += ((evs[e] & 127) == tid);
        offs[tid + 1] = c;
    }
    if (tid == 0) offs[0] = 0;
    __syncthreads();
    if (tid == 0) { for (int n = 0; n < N_; ++n) offs[n + 1] += offs[n]; }
    __syncthreads();
    if (tid < N_) {
        int p = offs[tid];
        for (int e = 0; e < E_; ++e) {
            int rec = evs[e];
            if ((rec & 127) == tid) {
                int s = rec >> 7;
                lists[p++] = s | ((e / DC_) << 9) | ((e % DC_) << 15);
            }
        }
    }
    __syncthreads();

    for (int i = tid; i < ZM; i += 1024) stateg[i] = (int)INIT_STATE;
    __syncthreads();

    for (int it = 0; it < iters; ++it) {
        for (int i = tid; i < ZN; i += 1024) {
            int z = i / N_, n = i - z * N_, t2 = 0;
            int kend = offs[n + 1];
            for (int k = offs[n]; k < kend; ++k) {
                int rec = lists[k];
                int s = rec & 511, m = (rec >> 9) & 63, j = rec >> 15;
                int zs = z - s; if (zs < 0) zs += Z_;
                t2 += decode2((unsigned)stateg[zs * M_ + m], j);
            }
            tot[i] = (short)t2;
        }
        __syncthreads();
        const float w = wlds[it];
        for (int i = tid; i < ZM; i += 1024) {
            int z = i / M_, m = i - z * M_;
            unsigned st = (unsigned)stateg[i];
            float m1 = 1e30f, m2 = 1e30f;
            int f = 0, negb = 0;
            #pragma unroll
            for (int j = 0; j < DC_; ++j) {
                int rec = evs[m * DC_ + j];
                int vn = rec & 127, s = rec >> 7;
                int zr = z + s; if (zr >= Z_) zr -= Z_;
                int c2 = decode2(st, j);
                int idx = zr * N_ + vn;
                float v = (xab[idx] + 0.5f * (float)tot[idx]) - 0.5f * (float)c2;
                v = fminf(fmaxf(v, -20.0f), 20.0f);
                negb |= (v < 0.0f) << j;
                float a = fabsf(v);
                if (a < m1) { m2 = m1; m1 = a; f = j; }
                else if (a < m2) { m2 = a; }
            }
            float r1 = fminf(fmaxf(rintf(w * m1 * 2.0f), -15.0f), 15.0f);
            float r2 = fminf(fmaxf(rintf(w * m2 * 2.0f), -15.0f), 15.0f);
            stateg[i] = (int)(unsigned)(negb | (f << 7) | (((int)r1 + 16) << 10) | (((int)r2 + 16) << 15));
        }
        __syncthreads();
    }

    for (int i = tid; i < ZN; i += 1024) {
        int z = i / N_, n = i - z * N_, t2 = 0;
        int kend = offs[n + 1];
        for (int k = offs[n]; k < kend; ++k) {
            int rec = lists[k];
            int s = rec & 511, m = (rec >> 9) & 63, j = rec >> 15;
            int zs = z - s; if (zs < 0) zs += Z_;
            t2 += decode2((unsigned)stateg[zs * M_ + m], j);
        }
        tot[i] = (short)t2;
    }
    __syncthreads();
    for (int i = tid; i < ZN; i += 1024) {
        int n = i / Z_, z = i - n * Z_;
        outb[i] = xab[z * N_ + n] + 0.5f * (float)tot[z * N_ + n];
    }
}

extern "C" void kernel_launch(void* const* d_in, const int* in_sizes, int n_in,
                              void* d_out, int out_size, void* d_ws, size_t ws_size,
                              hipStream_t stream) {
    const float* xa = (const float*)d_in[0];
    const float* cw = (const float*)d_in[1];
    const int* vn   = (const int*)d_in[2];
    // d_in[3] = cn_idx: repeat(arange(M), dc) by construction — implicit.
    const int* sh   = (const int*)d_in[4];
    int iters = in_sizes[1];
    float* outp = (float*)d_out;

    if (ws_size >= (size_t)WS_INTS * sizeof(int)) {
        int*         ws  = (int*)d_ws;
        float*       xat = (float*)d_ws + XAT_OFF;
        float*       lt  = (float*)d_ws + LT_OFF;
        signed char* msg = (signed char*)(ws + MSG_OFF);

        if (iters == 0) {   // out = transpose(xa); tables block is harmless
            hipLaunchKernelGGL(k_pre_tables, dim3(B_ * 6 + 1), dim3(384), 0, stream,
                               xa, vn, sh, ws, outp);
            return;
        }
        hipLaunchKernelGGL(k_pre_tables, dim3(B_ * 6 + 1), dim3(384), 0, stream,
                           xa, vn, sh, ws, xat);
        void* args[] = { (void*)&xat, (void*)&cw, (void*)&ws, (void*)&msg,
                         (void*)&lt, (void*)&outp, (void*)&iters };
        hipLaunchKernelGGL(k_persist, dim3(256), dim3(1024), 0, stream,
                           xat, cw, ws, msg, lt, outp, iters);
    } else {
        hipLaunchKernelGGL(ldpc_decode_kernel, dim3(B_), dim3(1024), 0, stream,
                           xa, cw, vn, sh, outp, iters);
    }
}

// Round 12
// 257.391 us; speedup vs baseline: 2.4055x; 1.2002x over previous
//
#include <hip/hip_runtime.h>

// Boosted neural LDPC min-sum decoder, MI355X — persistent kernel, batch-local
// flag barriers with NO L2 maintenance: all cross-block mutable data (msg, lt)
// goes through agent-scope RELAXED atomics (L2-bypass, coherent at L3), so the
// barrier is just drain + flag handshake. Read-only xat/tables stay L2-cached.
// Sizes fixed by setup_inputs(): B=32, Z=384, N=68, M=46, dc=7, E=322, iters=8.
#define B_   32
#define Z_   384
#define N_   68
#define M_   46
#define DC_  7
#define E_   (M_ * DC_)      // 322
#define ZN   (Z_ * N_)       // 26112
#define ZM   (Z_ * M_)       // 17664
#define MSB  (DC_ * ZM)      // 123648 bytes of messages per batch (7 planes)
#define ZM_S (ZM / 8)        // 2208 pass-B items per slice
#define ZN_S (ZN / 8)        // 3264 pass-A items per slice

// ---- workspace layout (int32 offsets) ----
#define XAT_OFF   0                          // float xat[B*ZN]   z-fastest
#define LT_OFF    (B_ * ZN)                  // float lt[B*ZN]    z-fastest
#define MSG_OFF   (2 * B_ * ZN)              // sbyte msg[B][7][ZM]  plane-major
#define MSG_INTS  ((B_ * MSB + 3) / 4)
#define FLG_OFF   (MSG_OFF + MSG_INTS)       // int flags[B][8] @ 64B stride
#define FLG_INTS  (B_ * 128)
#define EVS_OFF   (FLG_OFF + FLG_INTS)       // int evs[E]    (vn*Z)<<9 | s
#define OFFS_OFF  (EVS_OFF + E_)             // int offs[N+1] CSR per variable
#define LST_OFF   (OFFS_OFF + N_ + 1)        // int lists[E]  (j*ZM+m*Z)<<9 | s
#define WS_INTS   (LST_OFF + E_)             // ~2.67M ints ≈ 10.7 MB

#define ALDU(p)   __hip_atomic_load((p), __ATOMIC_RELAXED, __HIP_MEMORY_SCOPE_AGENT)
#define ASTU(p,v) __hip_atomic_store((p), (v), __ATOMIC_RELAXED, __HIP_MEMORY_SCOPE_AGENT)

// msg[b][j][m*Z+z] = c2v message on edge j of check (m,z), sign applied, in
// half-steps, range [-15,15]. Exact ints -> fp arithmetic identical to JAX ref.

// ==================== merged pre-transpose + table build + flag init ========
__global__ __launch_bounds__(384)
void k_pre_tables(const float* __restrict__ xa,
                  const int* __restrict__ vn_idx, const int* __restrict__ shifts,
                  int* __restrict__ ws, float* __restrict__ xat_dst)
{
    const int tid = threadIdx.x;
    if (blockIdx.x == B_ * 6) {
        __shared__ int vnl[E_];
        __shared__ int shl[E_];
        __shared__ int offs[N_ + 1];
        if (tid < E_) { vnl[tid] = vn_idx[tid]; shl[tid] = shifts[tid]; }
        for (int i = tid; i < FLG_INTS; i += 384) ws[FLG_OFF + i] = 0;
        __syncthreads();
        if (tid < N_) {
            int c = 0;
            for (int e = 0; e < E_; ++e) c += (vnl[e] == tid);
            offs[tid + 1] = c;
        }
        if (tid == 0) offs[0] = 0;
        __syncthreads();
        if (tid == 0) { for (int n = 0; n < N_; ++n) offs[n + 1] += offs[n]; }
        __syncthreads();
        if (tid < E_) ws[EVS_OFF + tid] = (vnl[tid] * Z_ << 9) | shl[tid];
        if (tid < N_ + 1) ws[OFFS_OFF + tid] = offs[tid];
        if (tid < N_) {
            int p = offs[tid];
            for (int e = 0; e < E_; ++e) {
                if (vnl[e] == tid) {
                    int m = e / DC_, j = e - m * DC_;
                    ws[LST_OFF + p++] = ((j * ZM + m * Z_) << 9) | shl[e];
                }
            }
        }
        return;
    }
    __shared__ float tile[N_ * 65];           // [n][zl], pad 65 to break conflicts
    const int x = blockIdx.x & 7;
    const int k = blockIdx.x >> 3;            // 0..23
    const int b = x + 8 * (k & 3);            // b % 8 == x  -> XCD locality
    const int t = k >> 2;                     // 0..5
    const int z0 = t * 64;
    const float* src = xa + (size_t)b * ZN + (size_t)z0 * N_;
    for (int i = tid; i < 64 * N_; i += 384) {  // contiguous 17 KB read
        int r = i / N_, n = i - r * N_;
        tile[n * 65 + r] = src[i];
    }
    __syncthreads();
    float* dst = xat_dst + (size_t)b * ZN + z0;
    for (int i = tid; i < 64 * N_; i += 384) {
        int n = i >> 6, zl = i & 63;
        dst[n * Z_ + zl] = tile[n * 65 + zl];
    }
}

// ==================== batch-local barrier — NO L2 wbl2/inv =================
// __syncthreads drains all prior vmem (compiler emits waitcnt vmcnt(0) before
// s_barrier); data ops are L2-bypassing atomics already acked at the coherent
// point, so a relaxed flag store + spin is a correct release/acquire.
__device__ __forceinline__ void bbar(int* flg, int sl, int phase)
{
    __syncthreads();
    __atomic_signal_fence(__ATOMIC_SEQ_CST);
    if (threadIdx.x == 0) ASTU(&flg[sl * 16], phase);
    if (threadIdx.x < 8) {
        while (ALDU(&flg[threadIdx.x * 16]) < phase)
            __builtin_amdgcn_s_sleep(1);
    }
    __atomic_signal_fence(__ATOMIC_SEQ_CST);
    __syncthreads();
}

// ==================== pass B: check-node update (slice) =====================
// Old msg read: one word-load per 4 lanes + shfl broadcast. New msg write:
// pack 4 lanes' bytes via shfl_down, one word-store per 4 lanes.
__device__ __forceinline__ void passB_slice(int lo, const float* __restrict__ srcf,
                                            const float* __restrict__ lta,
                                            unsigned* __restrict__ mw, float w,
                                            const int* __restrict__ evs,
                                            int use_init, int tid)
{
    const int hi = lo + ZM_S;
    for (int l = lo + tid; l < hi; l += 1024) {
        const int m = l / Z_;
        const int z = l - m * Z_;
        float m1 = 1e30f, m2 = 1e30f;
        int f = 0, negb = 0;
        #pragma unroll
        for (int j = 0; j < DC_; ++j) {
            int rec = evs[m * DC_ + j];
            int s = rec & 511;
            int zr = z + s; if (zr >= Z_) zr -= Z_;
            int c2 = 0;
            if (!use_init) {
                unsigned wd = 0;
                if ((tid & 3) == 0) wd = ALDU(mw + j * (ZM / 4) + (l >> 2));
                wd = (unsigned)__shfl((int)wd, (tid & 63) & ~3);
                c2 = ((int)wd << (24 - 8 * (l & 3))) >> 24;   // own old, exact int
            }
            // identical operand order to JAX: fl(fl(llr + tot) - c2v), then clip
            float v = (use_init ? srcf[(rec >> 9) + zr]
                                : __hip_atomic_load(lta + (rec >> 9) + zr,
                                      __ATOMIC_RELAXED, __HIP_MEMORY_SCOPE_AGENT))
                      - 0.5f * (float)c2;
            v = fminf(fmaxf(v, -20.0f), 20.0f);
            negb |= (v < 0.0f) << j;
            float a = fabsf(v);
            if (a < m1) { m2 = m1; m1 = a; f = j; }
            else if (a < m2) { m2 = a; }
        }
        // quantize-STE fwd: clip(rint(2*w*min)/2, +-7.5), int half-steps
        float r1 = fminf(fmaxf(rintf(w * m1 * 2.0f), -15.0f), 15.0f);
        float r2 = fminf(fmaxf(rintf(w * m2 * 2.0f), -15.0f), 15.0f);
        const int q1 = (int)r1, q2 = (int)r2;
        const int par = __popc(negb);
        #pragma unroll
        for (int j = 0; j < DC_; ++j) {
            int q  = (j == f) ? q2 : q1;
            int sj = (par - ((negb >> j) & 1)) & 1;   // parity of others' signs
            unsigned vb = (unsigned)((sj ? -q : q) & 255);
            unsigned b1 = (unsigned)__shfl_down((int)vb, 1);
            unsigned b2 = (unsigned)__shfl_down((int)vb, 2);
            unsigned b3 = (unsigned)__shfl_down((int)vb, 3);
            if ((tid & 3) == 0)
                ASTU(mw + j * (ZM / 4) + (l >> 2),
                     vb | (b1 << 8) | (b2 << 16) | (b3 << 24));
        }
    }
}

// ==================== pass A: variable totals (slice) =======================
__device__ __forceinline__ void passA_slice(int lo, const float* __restrict__ xb,
                                            const unsigned* __restrict__ mw,
                                            float* __restrict__ dst, int atomic_dst,
                                            const int* __restrict__ offs,
                                            const int* __restrict__ lists, int tid)
{
    const int hi = lo + ZN_S;
    for (int l = lo + tid; l < hi; l += 1024) {
        const int n = l / Z_;
        const int z = l - n * Z_;
        const int o = offs[n], e = offs[n + 1];   // wave-uniform (64 | Z)
        int t2 = 0;
        for (int k = o; k < e; ++k) {
            int rec = lists[k];
            int s = rec & 511;
            int zs = z - s; if (zs < 0) zs += Z_;
            int off = (rec >> 9) + zs;             // byte index, plane word-aligned
            unsigned wd = ALDU(mw + (off >> 2));
            t2 += ((int)wd << (24 - 8 * (off & 3))) >> 24;   // exact int half-steps
        }
        float val = xb[l] + 0.5f * (float)t2;      // fl(llr + tot)
        if (atomic_dst) __hip_atomic_store(dst + l, val, __ATOMIC_RELAXED,
                                           __HIP_MEMORY_SCOPE_AGENT);
        else            dst[l] = val;              // final out: normal store
    }
}

// ==================== persistent kernel: 256 blocks, batch-local sync =======
__global__ __launch_bounds__(1024)
void k_persist(const float* __restrict__ xat, const float* __restrict__ cw,
               int* __restrict__ ws, unsigned* __restrict__ msgw,
               float* __restrict__ lt, float* __restrict__ out, int iters)
{
    __shared__ int   evs[E_];
    __shared__ int   lists[E_];
    __shared__ int   offs[N_ + 1];
    __shared__ float wlds[8];
    const int tid = threadIdx.x;
    if (tid < E_) { evs[tid] = ws[EVS_OFF + tid]; lists[tid] = ws[LST_OFF + tid]; }
    if (tid < N_ + 1) offs[tid] = ws[OFFS_OFF + tid];
    if (tid < 8) wlds[tid] = cw[tid];
    __syncthreads();

    const int x  = blockIdx.x & 7;
    const int kk = blockIdx.x >> 3;
    const int b  = x + 8 * (kk & 3);           // b % 8 == x -> XCD locality
    const int sl = kk >> 2;                    // 0..7
    int* flg = ws + FLG_OFF + b * 128;

    const float* xb = xat + (size_t)b * ZN;
    float*       lb = lt + (size_t)b * ZN;
    unsigned*    mw = msgw + (size_t)b * (MSB / 4);
    const int bLo = sl * ZM_S;
    const int aLo = sl * ZN_S;
    int phase = 0;

    // it = 0: lt_old == xat (normal loads), all old c2v == 0
    passB_slice(bLo, xb, lb, mw, wlds[0], evs, 1, tid);
    for (int it = 1; it < iters; ++it) {
        bbar(flg, sl, ++phase);
        passA_slice(aLo, xb, mw, lb, 1, offs, lists, tid);
        bbar(flg, sl, ++phase);
        passB_slice(bLo, xb, lb, mw, wlds[it], evs, 0, tid);
    }
    bbar(flg, sl, ++phase);
    passA_slice(aLo, xb, mw, out + (size_t)b * ZN, 0, offs, lists, tid);
}

// ==================== fallback: single-block-per-batch kernel (small ws) ====
#define INIT_STATE ((16u << 10) | (16u << 15))
__device__ __forceinline__ int decode2(unsigned st, int j) {
    int neg   = (st >> j) & 1;
    int q1    = (int)((st >> 10) & 31) - 16;
    int q2    = (int)((st >> 15) & 31) - 16;
    int first = (int)((st >> 7) & 7);
    int q     = (j == first) ? q2 : q1;
    int par   = (__popc(st & 127u) - neg) & 1;
    return par ? -q : q;
}

__global__ __launch_bounds__(1024)
void ldpc_decode_kernel(const float* __restrict__ xa,
                        const float* __restrict__ cw,
                        const int*   __restrict__ vn_idx,
                        const int*   __restrict__ shifts,
                        float* out, int iters)
{
    __shared__ short tot[ZN];
    __shared__ int   evs[E_];
    __shared__ int   offs[N_ + 1];
    __shared__ int   lists[E_];
    __shared__ float wlds[8];

    const int tid = threadIdx.x;
    const int b   = blockIdx.x;
    const float* xab = xa + (size_t)b * ZN;
    float* outb = out + (size_t)b * ZN;
    int* stateg = (int*)outb;

    if (tid < E_) evs[tid] = vn_idx[tid] | (shifts[tid] << 7);
    if (tid < iters && tid < 8) wlds[tid] = cw[tid];
    __syncthreads();
    if (tid < N_) {
        int c = 0;
        for (int e = 0; e < E_; ++e) c += ((evs[e] & 127) == tid);
        offs[tid + 1] = c;
    }
    if (tid == 0) offs[0] = 0;
    __syncthreads();
    if (tid == 0) { for (int n = 0; n < N_; ++n) offs[n + 1] += offs[n]; }
    __syncthreads();
    if (tid < N_) {
        int p = offs[tid];
        for (int e = 0; e < E_; ++e) {
            int rec = evs[e];
            if ((rec & 127) == tid) {
                int s = rec >> 7;
                lists[p++] = s | ((e / DC_) << 9) | ((e % DC_) << 15);
            }
        }
    }
    __syncthreads();

    for (int i = tid; i < ZM; i += 1024) stateg[i] = (int)INIT_STATE;
    __syncthreads();

    for (int it = 0; it < iters; ++it) {
        for (int i = tid; i < ZN; i += 1024) {
            int z = i / N_, n = i - z * N_, t2 = 0;
            int kend = offs[n + 1];
            for (int k = offs[n]; k < kend; ++k) {
                int rec = lists[k];
                int s = rec & 511, m = (rec >> 9) & 63, j = rec >> 15;
                int zs = z - s; if (zs < 0) zs += Z_;
                t2 += decode2((unsigned)stateg[zs * M_ + m], j);
            }
            tot[i] = (short)t2;
        }
        __syncthreads();
        const float w = wlds[it];
        for (int i = tid; i < ZM; i += 1024) {
            int z = i / M_, m = i - z * M_;
            unsigned st = (unsigned)stateg[i];
            float m1 = 1e30f, m2 = 1e30f;
            int f = 0, negb = 0;
            #pragma unroll
            for (int j = 0; j < DC_; ++j) {
                int rec = evs[m * DC_ + j];
                int vn = rec & 127, s = rec >> 7;
                int zr = z + s; if (zr >= Z_) zr -= Z_;
                int c2 = decode2(st, j);
                int idx = zr * N_ + vn;
                float v = (xab[idx] + 0.5f * (float)tot[idx]) - 0.5f * (float)c2;
                v = fminf(fmaxf(v, -20.0f), 20.0f);
                negb |= (v < 0.0f) << j;
                float a = fabsf(v);
                if (a < m1) { m2 = m1; m1 = a; f = j; }
                else if (a < m2) { m2 = a; }
            }
            float r1 = fminf(fmaxf(rintf(w * m1 * 2.0f), -15.0f), 15.0f);
            float r2 = fminf(fmaxf(rintf(w * m2 * 2.0f), -15.0f), 15.0f);
            stateg[i] = (int)(unsigned)(negb | (f << 7) | (((int)r1 + 16) << 10) | (((int)r2 + 16) << 15));
        }
        __syncthreads();
    }

    for (int i = tid; i < ZN; i += 1024) {
        int z = i / N_, n = i - z * N_, t2 = 0;
        int kend = offs[n + 1];
        for (int k = offs[n]; k < kend; ++k) {
            int rec = lists[k];
            int s = rec & 511, m = (rec >> 9) & 63, j = rec >> 15;
            int zs = z - s; if (zs < 0) zs += Z_;
            t2 += decode2((unsigned)stateg[zs * M_ + m], j);
        }
        tot[i] = (short)t2;
    }
    __syncthreads();
    for (int i = tid; i < ZN; i += 1024) {
        int n = i / Z_, z = i - n * Z_;
        outb[i] = xab[z * N_ + n] + 0.5f * (float)tot[z * N_ + n];
    }
}

extern "C" void kernel_launch(void* const* d_in, const int* in_sizes, int n_in,
                              void* d_out, int out_size, void* d_ws, size_t ws_size,
                              hipStream_t stream) {
    const float* xa = (const float*)d_in[0];
    const float* cw = (const float*)d_in[1];
    const int* vn   = (const int*)d_in[2];
    // d_in[3] = cn_idx: repeat(arange(M), dc) by construction — implicit.
    const int* sh   = (const int*)d_in[4];
    int iters = in_sizes[1];
    float* outp = (float*)d_out;

    if (ws_size >= (size_t)WS_INTS * sizeof(int)) {
        int*      ws   = (int*)d_ws;
        float*    xat  = (float*)d_ws + XAT_OFF;
        float*    lt   = (float*)d_ws + LT_OFF;
        unsigned* msgw = (unsigned*)(ws + MSG_OFF);

        if (iters == 0) {   // out = transpose(xa); tables block is harmless
            hipLaunchKernelGGL(k_pre_tables, dim3(B_ * 6 + 1), dim3(384), 0, stream,
                               xa, vn, sh, ws, outp);
            return;
        }
        hipLaunchKernelGGL(k_pre_tables, dim3(B_ * 6 + 1), dim3(384), 0, stream,
                           xa, vn, sh, ws, xat);
        hipLaunchKernelGGL(k_persist, dim3(256), dim3(1024), 0, stream,
                           xat, cw, ws, msgw, lt, outp, iters);
    } else {
        hipLaunchKernelGGL(ldpc_decode_kernel, dim3(B_), dim3(1024), 0, stream,
                           xa, cw, vn, sh, outp, iters);
    }
}

// Round 13
// 230.371 us; speedup vs baseline: 2.6877x; 1.1173x over previous
//
#include <hip/hip_runtime.h>

// Boosted neural LDPC min-sum decoder, MI355X — persistent kernel, batch-local
// fence-free flag barriers (L2-bypass atomics for msg/lt), 2 blocks/CU with
// co-resident blocks from DIFFERENT batches so barrier spins overlap compute.
// Sizes fixed by setup_inputs(): B=32, Z=384, N=68, M=46, dc=7, E=322, iters=8.
#define B_   32
#define Z_   384
#define N_   68
#define M_   46
#define DC_  7
#define E_   (M_ * DC_)      // 322
#define ZN   (Z_ * N_)       // 26112
#define ZM   (Z_ * M_)       // 17664
#define MSB  (DC_ * ZM)      // 123648 bytes of messages per batch (7 planes)
#define NSL  16              // slices per batch
#define ZM_S (ZM / NSL)      // 1104 pass-B items per slice
#define ZN_S (ZN / NSL)      // 1632 pass-A items per slice

// ---- workspace layout (int32 offsets) ----
#define XAT_OFF   0                          // float xat[B*ZN]   z-fastest
#define LT_OFF    (B_ * ZN)                  // float lt[B*ZN]    z-fastest
#define MSG_OFF   (2 * B_ * ZN)              // sbyte msg[B][7][ZM]  plane-major
#define MSG_INTS  ((B_ * MSB + 3) / 4)
#define FLG_OFF   (MSG_OFF + MSG_INTS)       // int flags[B][NSL] @ 64B stride
#define FLG_INTS  (B_ * NSL * 16)
#define EVS_OFF   (FLG_OFF + FLG_INTS)       // int evs[E]    (vn*Z)<<9 | s
#define OFFS_OFF  (EVS_OFF + E_)             // int offs[N+1] CSR per variable
#define LST_OFF   (OFFS_OFF + N_ + 1)        // int lists[E]  (j*ZM+m*Z)<<9 | s
#define WS_INTS   (LST_OFF + E_)             // ~2.68M ints ≈ 10.7 MB

#define ALDU(p)   __hip_atomic_load((p), __ATOMIC_RELAXED, __HIP_MEMORY_SCOPE_AGENT)
#define ASTU(p,v) __hip_atomic_store((p), (v), __ATOMIC_RELAXED, __HIP_MEMORY_SCOPE_AGENT)

// msg[b][j][m*Z+z] = c2v message on edge j of check (m,z), sign applied, in
// half-steps, range [-15,15]. Exact ints -> fp arithmetic identical to JAX ref.

// ==================== merged pre-transpose + table build + flag init ========
__global__ __launch_bounds__(384)
void k_pre_tables(const float* __restrict__ xa,
                  const int* __restrict__ vn_idx, const int* __restrict__ shifts,
                  int* __restrict__ ws, float* __restrict__ xat_dst)
{
    const int tid = threadIdx.x;
    if (blockIdx.x == B_ * 6) {
        __shared__ int vnl[E_];
        __shared__ int shl[E_];
        __shared__ int offs[N_ + 1];
        if (tid < E_) { vnl[tid] = vn_idx[tid]; shl[tid] = shifts[tid]; }
        for (int i = tid; i < FLG_INTS; i += 384) ws[FLG_OFF + i] = 0;
        __syncthreads();
        if (tid < N_) {
            int c = 0;
            for (int e = 0; e < E_; ++e) c += (vnl[e] == tid);
            offs[tid + 1] = c;
        }
        if (tid == 0) offs[0] = 0;
        __syncthreads();
        if (tid == 0) { for (int n = 0; n < N_; ++n) offs[n + 1] += offs[n]; }
        __syncthreads();
        if (tid < E_) ws[EVS_OFF + tid] = (vnl[tid] * Z_ << 9) | shl[tid];
        if (tid < N_ + 1) ws[OFFS_OFF + tid] = offs[tid];
        if (tid < N_) {
            int p = offs[tid];
            for (int e = 0; e < E_; ++e) {
                if (vnl[e] == tid) {
                    int m = e / DC_, j = e - m * DC_;
                    ws[LST_OFF + p++] = ((j * ZM + m * Z_) << 9) | shl[e];
                }
            }
        }
        return;
    }
    __shared__ float tile[N_ * 65];           // [n][zl], pad 65 to break conflicts
    const int x = blockIdx.x & 7;
    const int k = blockIdx.x >> 3;            // 0..23
    const int b = x + 8 * (k & 3);            // b % 8 == x  -> XCD locality
    const int t = k >> 2;                     // 0..5
    const int z0 = t * 64;
    const float* src = xa + (size_t)b * ZN + (size_t)z0 * N_;
    for (int i = tid; i < 64 * N_; i += 384) {  // contiguous 17 KB read
        int r = i / N_, n = i - r * N_;
        tile[n * 65 + r] = src[i];
    }
    __syncthreads();
    float* dst = xat_dst + (size_t)b * ZN + z0;
    for (int i = tid; i < 64 * N_; i += 384) {
        int n = i >> 6, zl = i & 63;
        dst[n * Z_ + zl] = tile[n * 65 + zl];
    }
}

// ==================== batch-local barrier — NO L2 wbl2/inv =================
// Data ops are L2-bypassing atomics (acked at the coherent point before the
// pre-barrier __syncthreads' vmcnt drain), so a relaxed flag store + spin is a
// correct release/acquire. Signed compare: 0xAA poison is negative -> safe.
__device__ __forceinline__ void bbar(int* flg, int sl, int phase)
{
    __syncthreads();
    __atomic_signal_fence(__ATOMIC_SEQ_CST);
    if (threadIdx.x == 0) ASTU(&flg[sl * 16], phase);
    if (threadIdx.x < NSL) {
        while (ALDU(&flg[threadIdx.x * 16]) < phase)
            __builtin_amdgcn_s_sleep(1);
    }
    __atomic_signal_fence(__ATOMIC_SEQ_CST);
    __syncthreads();
}

// ==================== pass B: check-node update (slice) =====================
__device__ __forceinline__ void passB_slice(int lo, const float* __restrict__ srcf,
                                            const float* __restrict__ lta,
                                            unsigned* __restrict__ mw, float w,
                                            const int* __restrict__ evs,
                                            int use_init, int tid)
{
    const int hi = lo + ZM_S;
    for (int l = lo + tid; l < hi; l += 1024) {
        const int m = l / Z_;
        const int z = l - m * Z_;
        float m1 = 1e30f, m2 = 1e30f;
        int f = 0, negb = 0;
        #pragma unroll
        for (int j = 0; j < DC_; ++j) {
            int rec = evs[m * DC_ + j];
            int s = rec & 511;
            int zr = z + s; if (zr >= Z_) zr -= Z_;
            int c2 = 0;
            if (!use_init) {
                unsigned wd = 0;
                if ((tid & 3) == 0) wd = ALDU(mw + j * (ZM / 4) + (l >> 2));
                wd = (unsigned)__shfl((int)wd, (tid & 63) & ~3);
                c2 = ((int)wd << (24 - 8 * (l & 3))) >> 24;   // own old, exact int
            }
            // identical operand order to JAX: fl(fl(llr + tot) - c2v), then clip
            float v = (use_init ? srcf[(rec >> 9) + zr]
                                : __hip_atomic_load(lta + (rec >> 9) + zr,
                                      __ATOMIC_RELAXED, __HIP_MEMORY_SCOPE_AGENT))
                      - 0.5f * (float)c2;
            v = fminf(fmaxf(v, -20.0f), 20.0f);
            negb |= (v < 0.0f) << j;
            float a = fabsf(v);
            if (a < m1) { m2 = m1; m1 = a; f = j; }
            else if (a < m2) { m2 = a; }
        }
        // quantize-STE fwd: clip(rint(2*w*min)/2, +-7.5), int half-steps
        float r1 = fminf(fmaxf(rintf(w * m1 * 2.0f), -15.0f), 15.0f);
        float r2 = fminf(fmaxf(rintf(w * m2 * 2.0f), -15.0f), 15.0f);
        const int q1 = (int)r1, q2 = (int)r2;
        const int par = __popc(negb);
        #pragma unroll
        for (int j = 0; j < DC_; ++j) {
            int q  = (j == f) ? q2 : q1;
            int sj = (par - ((negb >> j) & 1)) & 1;   // parity of others' signs
            unsigned vb = (unsigned)((sj ? -q : q) & 255);
            unsigned b1 = (unsigned)__shfl_down((int)vb, 1);
            unsigned b2 = (unsigned)__shfl_down((int)vb, 2);
            unsigned b3 = (unsigned)__shfl_down((int)vb, 3);
            if ((tid & 3) == 0)
                ASTU(mw + j * (ZM / 4) + (l >> 2),
                     vb | (b1 << 8) | (b2 << 16) | (b3 << 24));
        }
    }
}

// ==================== pass A: variable totals (slice) =======================
__device__ __forceinline__ void passA_slice(int lo, const float* __restrict__ xb,
                                            const unsigned* __restrict__ mw,
                                            float* __restrict__ dst, int atomic_dst,
                                            const int* __restrict__ offs,
                                            const int* __restrict__ lists, int tid)
{
    const int hi = lo + ZN_S;
    for (int l = lo + tid; l < hi; l += 1024) {
        const int n = l / Z_;
        const int z = l - n * Z_;
        const int o = offs[n], e = offs[n + 1];
        int t2 = 0;
        for (int k = o; k < e; ++k) {
            int rec = lists[k];
            int s = rec & 511;
            int zs = z - s; if (zs < 0) zs += Z_;
            int off = (rec >> 9) + zs;             // byte index, plane word-aligned
            unsigned wd = ALDU(mw + (off >> 2));
            t2 += ((int)wd << (24 - 8 * (off & 3))) >> 24;   // exact int half-steps
        }
        float val = xb[l] + 0.5f * (float)t2;      // fl(llr + tot)
        if (atomic_dst) __hip_atomic_store(dst + l, val, __ATOMIC_RELAXED,
                                           __HIP_MEMORY_SCOPE_AGENT);
        else            dst[l] = val;              // final out: normal store
    }
}

// ==================== persistent kernel: 512 blocks (2/CU), batch-local sync
// g: x=g&7 (XCD), u=g>>3, p=u>>4, w=u&15 -> b = x+8*((w+p)&3), sl = w.
// Co-resident blocks (g, g+256) differ in p by 2 -> DIFFERENT batches, so one
// block's barrier spin is hidden by the other's compute.
__global__ __launch_bounds__(1024)
void k_persist(const float* __restrict__ xat, const float* __restrict__ cw,
               int* __restrict__ ws, unsigned* __restrict__ msgw,
               float* __restrict__ lt, float* __restrict__ out, int iters)
{
    __shared__ int   evs[E_];
    __shared__ int   lists[E_];
    __shared__ int   offs[N_ + 1];
    __shared__ float wlds[8];
    const int tid = threadIdx.x;
    if (tid < E_) { evs[tid] = ws[EVS_OFF + tid]; lists[tid] = ws[LST_OFF + tid]; }
    if (tid < N_ + 1) offs[tid] = ws[OFFS_OFF + tid];
    if (tid < 8) wlds[tid] = cw[tid];
    __syncthreads();

    const int x = blockIdx.x & 7;
    const int u = blockIdx.x >> 3;             // 0..63
    const int p = u >> 4;                      // 0..3
    const int w = u & 15;                      // 0..15
    const int b = x + 8 * ((w + p) & 3);       // b % 8 == x -> XCD locality
    const int sl = w;                          // 0..15
    int* flg = ws + FLG_OFF + b * (NSL * 16);

    const float* xb = xat + (size_t)b * ZN;
    float*       lb = lt + (size_t)b * ZN;
    unsigned*    mw = msgw + (size_t)b * (MSB / 4);
    const int bLo = sl * ZM_S;
    const int aLo = sl * ZN_S;
    int phase = 0;

    // it = 0: lt_old == xat (normal loads), all old c2v == 0
    passB_slice(bLo, xb, lb, mw, wlds[0], evs, 1, tid);
    for (int it = 1; it < iters; ++it) {
        bbar(flg, sl, ++phase);
        passA_slice(aLo, xb, mw, lb, 1, offs, lists, tid);
        bbar(flg, sl, ++phase);
        passB_slice(bLo, xb, lb, mw, wlds[it], evs, 0, tid);
    }
    bbar(flg, sl, ++phase);
    passA_slice(aLo, xb, mw, out + (size_t)b * ZN, 0, offs, lists, tid);
}

// ==================== fallback: single-block-per-batch kernel (small ws) ====
#define INIT_STATE ((16u << 10) | (16u << 15))
__device__ __forceinline__ int decode2(unsigned st, int j) {
    int neg   = (st >> j) & 1;
    int q1    = (int)((st >> 10) & 31) - 16;
    int q2    = (int)((st >> 15) & 31) - 16;
    int first = (int)((st >> 7) & 7);
    int q     = (j == first) ? q2 : q1;
    int par   = (__popc(st & 127u) - neg) & 1;
    return par ? -q : q;
}

__global__ __launch_bounds__(1024)
void ldpc_decode_kernel(const float* __restrict__ xa,
                        const float* __restrict__ cw,
                        const int*   __restrict__ vn_idx,
                        const int*   __restrict__ shifts,
                        float* out, int iters)
{
    __shared__ short tot[ZN];
    __shared__ int   evs[E_];
    __shared__ int   offs[N_ + 1];
    __shared__ int   lists[E_];
    __shared__ float wlds[8];

    const int tid = threadIdx.x;
    const int b   = blockIdx.x;
    const float* xab = xa + (size_t)b * ZN;
    float* outb = out + (size_t)b * ZN;
    int* stateg = (int*)outb;

    if (tid < E_) evs[tid] = vn_idx[tid] | (shifts[tid] << 7);
    if (tid < iters && tid < 8) wlds[tid] = cw[tid];
    __syncthreads();
    if (tid < N_) {
        int c = 0;
        for (int e = 0; e < E_; ++e) c += ((evs[e] & 127) == tid);
        offs[tid + 1] = c;
    }
    if (tid == 0) offs[0] = 0;
    __syncthreads();
    if (tid == 0) { for (int n = 0; n < N_; ++n) offs[n + 1] += offs[n]; }
    __syncthreads();
    if (tid < N_) {
        int p = offs[tid];
        for (int e = 0; e < E_; ++e) {
            int rec = evs[e];
            if ((rec & 127) == tid) {
                int s = rec >> 7;
                lists[p++] = s | ((e / DC_) << 9) | ((e % DC_) << 15);
            }
        }
    }
    __syncthreads();

    for (int i = tid; i < ZM; i += 1024) stateg[i] = (int)INIT_STATE;
    __syncthreads();

    for (int it = 0; it < iters; ++it) {
        for (int i = tid; i < ZN; i += 1024) {
            int z = i / N_, n = i - z * N_, t2 = 0;
            int kend = offs[n + 1];
            for (int k = offs[n]; k < kend; ++k) {
                int rec = lists[k];
                int s = rec & 511, m = (rec >> 9) & 63, j = rec >> 15;
                int zs = z - s; if (zs < 0) zs += Z_;
                t2 += decode2((unsigned)stateg[zs * M_ + m], j);
            }
            tot[i] = (short)t2;
        }
        __syncthreads();
        const float w = wlds[it];
        for (int i = tid; i < ZM; i += 1024) {
            int z = i / M_, m = i - z * M_;
            unsigned st = (unsigned)stateg[i];
            float m1 = 1e30f, m2 = 1e30f;
            int f = 0, negb = 0;
            #pragma unroll
            for (int j = 0; j < DC_; ++j) {
                int rec = evs[m * DC_ + j];
                int vn = rec & 127, s = rec >> 7;
                int zr = z + s; if (zr >= Z_) zr -= Z_;
                int c2 = decode2(st, j);
                int idx = zr * N_ + vn;
                float v = (xab[idx] + 0.5f * (float)tot[idx]) - 0.5f * (float)c2;
                v = fminf(fmaxf(v, -20.0f), 20.0f);
                negb |= (v < 0.0f) << j;
                float a = fabsf(v);
                if (a < m1) { m2 = m1; m1 = a; f = j; }
                else if (a < m2) { m2 = a; }
            }
            float r1 = fminf(fmaxf(rintf(w * m1 * 2.0f), -15.0f), 15.0f);
            float r2 = fminf(fmaxf(rintf(w * m2 * 2.0f), -15.0f), 15.0f);
            stateg[i] = (int)(unsigned)(negb | (f << 7) | (((int)r1 + 16) << 10) | (((int)r2 + 16) << 15));
        }
        __syncthreads();
    }

    for (int i = tid; i < ZN; i += 1024) {
        int z = i / N_, n = i - z * N_, t2 = 0;
        int kend = offs[n + 1];
        for (int k = offs[n]; k < kend; ++k) {
            int rec = lists[k];
            int s = rec & 511, m = (rec >> 9) & 63, j = rec >> 15;
            int zs = z - s; if (zs < 0) zs += Z_;
            t2 += decode2((unsigned)stateg[zs * M_ + m], j);
        }
        tot[i] = (short)t2;
    }
    __syncthreads();
    for (int i = tid; i < ZN; i += 1024) {
        int n = i / Z_, z = i - n * Z_;
        outb[i] = xab[z * N_ + n] + 0.5f * (float)tot[z * N_ + n];
    }
}

extern "C" void kernel_launch(void* const* d_in, const int* in_sizes, int n_in,
                              void* d_out, int out_size, void* d_ws, size_t ws_size,
                              hipStream_t stream) {
    const float* xa = (const float*)d_in[0];
    const float* cw = (const float*)d_in[1];
    const int* vn   = (const int*)d_in[2];
    // d_in[3] = cn_idx: repeat(arange(M), dc) by construction — implicit.
    const int* sh   = (const int*)d_in[4];
    int iters = in_sizes[1];
    float* outp = (float*)d_out;

    if (ws_size >= (size_t)WS_INTS * sizeof(int)) {
        int*      ws   = (int*)d_ws;
        float*    xat  = (float*)d_ws + XAT_OFF;
        float*    lt   = (float*)d_ws + LT_OFF;
        unsigned* msgw = (unsigned*)(ws + MSG_OFF);

        if (iters == 0) {   // out = transpose(xa); tables block is harmless
            hipLaunchKernelGGL(k_pre_tables, dim3(B_ * 6 + 1), dim3(384), 0, stream,
                               xa, vn, sh, ws, outp);
            return;
        }
        hipLaunchKernelGGL(k_pre_tables, dim3(B_ * 6 + 1), dim3(384), 0, stream,
                           xa, vn, sh, ws, xat);
        hipLaunchKernelGGL(k_persist, dim3(512), dim3(1024), 0, stream,
                           xat, cw, ws, msgw, lt, outp, iters);
    } else {
        hipLaunchKernelGGL(ldpc_decode_kernel, dim3(B_), dim3(1024), 0, stream,
                           xa, cw, vn, sh, outp, iters);
    }
}

// Round 14
// 218.293 us; speedup vs baseline: 2.8364x; 1.0553x over previous
//
#include <hip/hip_runtime.h>

// Boosted neural LDPC min-sum decoder, MI355X — ONE persistent dispatch.
// 512 blocks (2/CU, co-resident blocks = different batches), batch-local
// fence-free flag barriers, L2-bypass atomics for all cross-block mutable data
// (int16 tot + int8 msg planes), cached read-only xat, in-kernel transpose+tables.
// Sizes fixed by setup_inputs(): B=32, Z=384, N=68, M=46, dc=7, E=322, iters=8.
#define B_   32
#define Z_   384
#define N_   68
#define M_   46
#define DC_  7
#define E_   (M_ * DC_)      // 322
#define ZN   (Z_ * N_)       // 26112
#define ZM   (Z_ * M_)       // 17664
#define MSB  (DC_ * ZM)      // 123648 msg bytes per batch (7 planes)
#define NSL  16              // slices per batch
#define ZM_S (ZM / NSL)      // 1104 pass-B items per slice
#define ZN_S (ZN / NSL)      // 1632 pass-A items per slice
#define W_   8               // padded gather width in pass A (dv avg 4.7)

// ---- workspace layout (int32 offsets) ----
#define XAT_OFF   0                          // float xat[B*ZN]       z-fastest
#define TOT_OFF   (B_ * ZN)                  // short tot[B*ZN]       z-fastest
#define MSG_OFF   (TOT_OFF + B_ * ZN / 2)    // sbyte msg[B][7][ZM]   plane-major
#define MSG_INTS  (B_ * MSB / 4)
#define FLG_OFF   (MSG_OFF + MSG_INTS)       // int flags[B][NSL] @ 64B stride
#define WS_INTS   (FLG_OFF + B_ * NSL * 16)  // ~2.25M ints ≈ 9.0 MB

#define ALD(p)    __hip_atomic_load((p), __ATOMIC_RELAXED, __HIP_MEMORY_SCOPE_AGENT)
#define AST(p,v)  __hip_atomic_store((p), (v), __ATOMIC_RELAXED, __HIP_MEMORY_SCOPE_AGENT)

// msg[b][j][m*Z+z] = c2v message on edge j of check (m,z), sign applied, in
// half-steps [-15,15]. tot[b][n*Z+z] = sum of incoming msgs (exact int).
// All fp ops replicate JAX's operand order bit-exactly.

// ==================== batch-local barrier — no L2 maintenance ==============
// Mutable data moves via L2-bypass atomics (acked at the coherent point before
// the pre-barrier __syncthreads' vmcnt drain), so a relaxed flag store + spin
// is a correct release/acquire. Signed compare: 0xAA ws-poison is negative.
__device__ __forceinline__ void bbar(int* flg, int sl, int phase)
{
    __syncthreads();
    __atomic_signal_fence(__ATOMIC_SEQ_CST);
    if (threadIdx.x == 0) AST(&flg[sl * 16], phase);
    if (threadIdx.x < NSL) {
        while (ALD(&flg[threadIdx.x * 16]) < phase)
            __builtin_amdgcn_s_sleep(1);
    }
    __atomic_signal_fence(__ATOMIC_SEQ_CST);
    __syncthreads();
}

// ==================== the whole decoder, one dispatch ======================
// g: x=g&7 (XCD), u=g>>3, p=u>>4, w=u&15 -> b = x+8*((w+p)&3), sl = w.
// Co-resident blocks (g, g+256) have different p -> DIFFERENT batches: one
// block's barrier spin is hidden by the other's compute.
__global__ __launch_bounds__(1024, 8)
void k_persist(const float* __restrict__ xa, const float* __restrict__ cw,
               const int* __restrict__ vn_idx, const int* __restrict__ shifts,
               int* __restrict__ ws, float* __restrict__ out, int iters)
{
    __shared__ int   evs[E_];        // pass-B recs: (vn*Z)<<9 | s   (check-major)
    __shared__ int   lists[E_];      // pass-A CSR recs: (j*ZM+m*Z)<<9 | s
    __shared__ int   plist[N_ * W_]; // padded pass-A recs, valid bit 28
    __shared__ int   offs[N_ + 1];
    __shared__ float wlds[8];
    __shared__ float tile[N_ * 65];  // transpose tile (also temp for build)

    const int tid = threadIdx.x;

    // ---- table build (every block, identical, ~1 µs) ----
    int* vnl = (int*)tile;
    int* shl = vnl + E_;
    if (tid < E_) { vnl[tid] = vn_idx[tid]; shl[tid] = shifts[tid]; }
    if (tid < 8) wlds[tid] = cw[tid];
    __syncthreads();
    if (tid < N_) {
        int c = 0;
        for (int e = 0; e < E_; ++e) c += (vnl[e] == tid);
        offs[tid + 1] = c;
    }
    if (tid == 0) offs[0] = 0;
    __syncthreads();
    if (tid == 0) { for (int n = 0; n < N_; ++n) offs[n + 1] += offs[n]; }
    __syncthreads();
    if (tid < E_) evs[tid] = (vnl[tid] * Z_ << 9) | shl[tid];
    if (tid < N_) {
        int p = offs[tid];
        for (int e = 0; e < E_; ++e) {
            if (vnl[e] == tid) {
                int m = e / DC_, j = e - m * DC_;
                lists[p++] = ((j * ZM + m * Z_) << 9) | shl[e];
            }
        }
    }
    __syncthreads();
    if (tid < N_) {
        int dv = offs[tid + 1] - offs[tid];
        #pragma unroll
        for (int k = 0; k < W_; ++k)   // dummy slot: off=0,s=0 -> safe masked load
            plist[tid * W_ + k] = (k < dv) ? (lists[offs[tid] + k] | (1 << 28)) : 0;
    }
    __syncthreads();

    // ---- block -> (batch, slice) mapping ----
    const int x = blockIdx.x & 7;
    const int u = blockIdx.x >> 3;
    const int p = u >> 4;
    const int w = u & 15;
    const int b  = x + 8 * ((w + p) & 3);     // b % 8 == x -> XCD locality
    const int sl = w;
    int*          flg = ws + FLG_OFF + b * (NSL * 16);
    float*        xb  = (float*)(ws + XAT_OFF) + (size_t)b * ZN;
    short*        tw  = (short*)(ws + TOT_OFF) + (size_t)b * ZN;
    signed char*  mb  = (signed char*)(ws + MSG_OFF) + (size_t)b * MSB;
    int phase = 0;

    // ---- transpose this batch's slab: xat[b][n][z] = xa[b][z][n] ----
    // (bypass stores -> visible at coherent point; consumers first-touch after
    //  the barrier, so correctness does not depend on block->XCD placement.)
    if (sl < 6) {
        const int z0 = sl * 64;
        const float* src = xa + (size_t)b * ZN + (size_t)z0 * N_;
        for (int i = tid; i < 64 * N_; i += 1024) {   // contiguous 17 KB read
            int r = i / N_, n = i - r * N_;
            tile[n * 65 + r] = src[i];
        }
        __syncthreads();
        if (iters == 0) {                             // out = transpose(xa)
            float* dst = out + (size_t)b * ZN + z0;
            for (int i = tid; i < 64 * N_; i += 1024) {
                int n = i >> 6, zl = i & 63;
                dst[n * Z_ + zl] = tile[n * 65 + zl];
            }
            return;
        }
        for (int i = tid; i < 64 * N_; i += 1024) {
            int n = i >> 6, zl = i & 63;
            AST(xb + n * Z_ + z0 + zl, tile[n * 65 + zl]);
        }
    }
    if (iters == 0) return;
    bbar(flg, sl, ++phase);

    // ================= iteration loop: B0, (A,B)x(iters-1), A_final ========
    for (int it = 0; it < iters; ++it) {
        // ---- pass B: check-node update ----
        // v = fl(fl(xat + 0.5*tot) - 0.5*c2)  — bit-identical to fl(lt - c2v).
        const float wgt = wlds[it];
        const int use_init = (it == 0);
        {
            const int lo = sl * ZM_S, hi2 = lo + ZM_S;
            for (int l = lo + tid; l < hi2; l += 1024) {
                const int m = l / Z_;
                const int z = l - m * Z_;
                float m1 = 1e30f, m2 = 1e30f;
                int f = 0, negb = 0;
                #pragma unroll
                for (int j = 0; j < DC_; ++j) {
                    int rec = evs[m * DC_ + j];
                    int s = rec & 511;
                    int zr = z + s; if (zr >= Z_) zr -= Z_;
                    int off = rec >> 9;                     // vn*Z
                    int t2v = 0, c2 = 0;
                    if (!use_init) {
                        t2v = (int)ALD(tw + off + zr);      // exact int half-steps
                        c2  = (int)ALD(mb + j * ZM + l);    // own old msg
                    }
                    float base = xb[off + zr] + 0.5f * (float)t2v;  // fl(llr+tot)
                    float v = base - 0.5f * (float)c2;              // fl(.. - c2v)
                    v = fminf(fmaxf(v, -20.0f), 20.0f);
                    negb |= (v < 0.0f) << j;
                    float a = fabsf(v);
                    if (a < m1) { m2 = m1; m1 = a; f = j; }
                    else if (a < m2) { m2 = a; }
                }
                // quantize-STE fwd: clip(rint(2*w*min)/2, +-7.5), int half-steps
                float r1 = fminf(fmaxf(rintf(wgt * m1 * 2.0f), -15.0f), 15.0f);
                float r2 = fminf(fmaxf(rintf(wgt * m2 * 2.0f), -15.0f), 15.0f);
                const int q1 = (int)r1, q2 = (int)r2;
                const int par = __popc(negb);
                #pragma unroll
                for (int j = 0; j < DC_; ++j) {
                    int q  = (j == f) ? q2 : q1;
                    int sj = (par - ((negb >> j) & 1)) & 1; // parity of others
                    AST(mb + j * ZM + l, (signed char)(sj ? -q : q));
                }
            }
        }
        bbar(flg, sl, ++phase);

        // ---- pass A: variable totals (8 independent padded gathers) ----
        const int final_it = (it == iters - 1);
        {
            const int lo = sl * ZN_S, hi2 = lo + ZN_S;
            for (int l = lo + tid; l < hi2; l += 1024) {
                const int n = l / Z_;
                const int z = l - n * Z_;
                int t2 = 0;
                #pragma unroll
                for (int k = 0; k < W_; ++k) {
                    int rec = plist[n * W_ + k];
                    int s = rec & 511;
                    int zs = z - s; if (zs < 0) zs += Z_;
                    int off = (rec >> 9) & 0x1FFFF;         // j*ZM + m*Z
                    int v = (int)ALD(mb + off + zs);        // safe for dummy slot
                    t2 += (rec >> 28) ? v : 0;
                }
                int dvn = offs[n + 1] - offs[n];
                if (dvn > W_) {                              // rare tail
                    for (int k = W_; k < dvn; ++k) {
                        int rec = lists[offs[n] + k];
                        int s = rec & 511;
                        int zs = z - s; if (zs < 0) zs += Z_;
                        t2 += (int)ALD(mb + (rec >> 9) + zs);
                    }
                }
                if (final_it)
                    out[(size_t)b * ZN + l] = xb[l] + 0.5f * (float)t2; // fl(llr+tot)
                else
                    AST(tw + l, (short)t2);
            }
        }
        if (!final_it) bbar(flg, sl, ++phase);
    }
}

// ==================== fallback: single-block-per-batch kernel (small ws) ====
#define INIT_STATE ((16u << 10) | (16u << 15))
__device__ __forceinline__ int decode2(unsigned st, int j) {
    int neg   = (st >> j) & 1;
    int q1    = (int)((st >> 10) & 31) - 16;
    int q2    = (int)((st >> 15) & 31) - 16;
    int first = (int)((st >> 7) & 7);
    int q     = (j == first) ? q2 : q1;
    int par   = (__popc(st & 127u) - neg) & 1;
    return par ? -q : q;
}

__global__ __launch_bounds__(1024)
void ldpc_decode_kernel(const float* __restrict__ xa,
                        const float* __restrict__ cw,
                        const int*   __restrict__ vn_idx,
                        const int*   __restrict__ shifts,
                        float* out, int iters)
{
    __shared__ short tot[ZN];
    __shared__ int   evs[E_];
    __shared__ int   offs[N_ + 1];
    __shared__ int   lists[E_];
    __shared__ float wlds[8];

    const int tid = threadIdx.x;
    const int b   = blockIdx.x;
    const float* xab = xa + (size_t)b * ZN;
    float* outb = out + (size_t)b * ZN;
    int* stateg = (int*)outb;

    if (tid < E_) evs[tid] = vn_idx[tid] | (shifts[tid] << 7);
    if (tid < iters && tid < 8) wlds[tid] = cw[tid];
    __syncthreads();
    if (tid < N_) {
        int c = 0;
        for (int e = 0; e < E_; ++e) c += ((evs[e] & 127) == tid);
        offs[tid + 1] = c;
    }
    if (tid == 0) offs[0] = 0;
    __syncthreads();
    if (tid == 0) { for (int n = 0; n < N_; ++n) offs[n + 1] += offs[n]; }
    __syncthreads();
    if (tid < N_) {
        int p = offs[tid];
        for (int e = 0; e < E_; ++e) {
            int rec = evs[e];
            if ((rec & 127) == tid) {
                int s = rec >> 7;
                lists[p++] = s | ((e / DC_) << 9) | ((e % DC_) << 15);
            }
        }
    }
    __syncthreads();

    for (int i = tid; i < ZM; i += 1024) stateg[i] = (int)INIT_STATE;
    __syncthreads();

    for (int it = 0; it < iters; ++it) {
        for (int i = tid; i < ZN; i += 1024) {
            int z = i / N_, n = i - z * N_, t2 = 0;
            int kend = offs[n + 1];
            for (int k = offs[n]; k < kend; ++k) {
                int rec = lists[k];
                int s = rec & 511, m = (rec >> 9) & 63, j = rec >> 15;
                int zs = z - s; if (zs < 0) zs += Z_;
                t2 += decode2((unsigned)stateg[zs * M_ + m], j);
            }
            tot[i] = (short)t2;
        }
        __syncthreads();
        const float w = wlds[it];
        for (int i = tid; i < ZM; i += 1024) {
            int z = i / M_, m = i - z * M_;
            unsigned st = (unsigned)stateg[i];
            float m1 = 1e30f, m2 = 1e30f;
            int f = 0, negb = 0;
            #pragma unroll
            for (int j = 0; j < DC_; ++j) {
                int rec = evs[m * DC_ + j];
                int vn = rec & 127, s = rec >> 7;
                int zr = z + s; if (zr >= Z_) zr -= Z_;
                int c2 = decode2(st, j);
                int idx = zr * N_ + vn;
                float v = (xab[idx] + 0.5f * (float)tot[idx]) - 0.5f * (float)c2;
                v = fminf(fmaxf(v, -20.0f), 20.0f);
                negb |= (v < 0.0f) << j;
                float a = fabsf(v);
                if (a < m1) { m2 = m1; m1 = a; f = j; }
                else if (a < m2) { m2 = a; }
            }
            float r1 = fminf(fmaxf(rintf(w * m1 * 2.0f), -15.0f), 15.0f);
            float r2 = fminf(fmaxf(rintf(w * m2 * 2.0f), -15.0f), 15.0f);
            stateg[i] = (int)(unsigned)(negb | (f << 7) | (((int)r1 + 16) << 10) | (((int)r2 + 16) << 15));
        }
        __syncthreads();
    }

    for (int i = tid; i < ZN; i += 1024) {
        int z = i / N_, n = i - z * N_, t2 = 0;
        int kend = offs[n + 1];
        for (int k = offs[n]; k < kend; ++k) {
            int rec = lists[k];
            int s = rec & 511, m = (rec >> 9) & 63, j = rec >> 15;
            int zs = z - s; if (zs < 0) zs += Z_;
            t2 += decode2((unsigned)stateg[zs * M_ + m], j);
        }
        tot[i] = (short)t2;
    }
    __syncthreads();
    for (int i = tid; i < ZN; i += 1024) {
        int n = i / Z_, z = i - n * Z_;
        outb[i] = xab[z * N_ + n] + 0.5f * (float)tot[z * N_ + n];
    }
}

extern "C" void kernel_launch(void* const* d_in, const int* in_sizes, int n_in,
                              void* d_out, int out_size, void* d_ws, size_t ws_size,
                              hipStream_t stream) {
    const float* xa = (const float*)d_in[0];
    const float* cw = (const float*)d_in[1];
    const int* vn   = (const int*)d_in[2];
    // d_in[3] = cn_idx: repeat(arange(M), dc) by construction — implicit.
    const int* sh   = (const int*)d_in[4];
    int iters = in_sizes[1];
    float* outp = (float*)d_out;

    if (ws_size >= (size_t)WS_INTS * sizeof(int)) {
        hipLaunchKernelGGL(k_persist, dim3(512), dim3(1024), 0, stream,
                           xa, cw, vn, sh, (int*)d_ws, outp, iters);
    } else {
        hipLaunchKernelGGL(ldpc_decode_kernel, dim3(B_), dim3(1024), 0, stream,
                           xa, cw, vn, sh, outp, iters);
    }
}